// Round 1
// baseline (129.748 us; speedup 1.0000x reference)
//
#include <hip/hip_runtime.h>
#include <hip/hip_bf16.h>

// PositionalBias: pbv[n,j,h,d] = sum_{l=1..2046} w[h,|j-l|] * v[n,l,h,d]  (j in 1..2046, else 0)
//                 z_pb[l,h]    = sum_{j=1..2046} w[h,|l-j|]               (l in 1..2046, else 0)
// B=4, S=2048, H=12, D=64. Outputs fp32: pbv (6291456) then z_pb (24576).
//
// TWO dispatches:
//  1) prep_kernel (396 blocks): blocks 0..383 transpose+convert v -> g_vt[n][h][d][l] bf16
//     with border columns l=0 / l=2047 zeroed (this removes ALL f2bf + masking VALU from
//     the GEMM hot loop and makes a B-fragment one aligned dwordx4). Blocks 384..395 = z_pb.
//  2) gemm_kernel (768 blocks): Toeplitz GEMM. Per iter per wave: 2 global dwordx4 (B),
//     4 ds_read_b128 (A sliding window from 8x pre-shifted LDS Toeplitz table), 16 MFMA.

typedef short short8 __attribute__((ext_vector_type(8)));   // 8 x bf16 bits (4 VGPRs)
typedef float floatx4 __attribute__((ext_vector_type(4)));  // MFMA accumulator

#define TL 2280   // A-table length per shifted copy (shorts); 8 copies = 36.5 KB LDS

// v^T in bf16: [n][h][d][l], l contiguous. 4*12*64*2048 shorts = 12.58 MB.
__device__ __attribute__((aligned(16))) short g_vt[4 * 12 * 64 * 2048];

__device__ __forceinline__ unsigned short f2bf(float f) {
  union { __hip_bfloat16 b; unsigned short u; } cv;
  cv.b = __float2bfloat16(f);  // RNE
  return cv.u;
}

// ---------------- dispatch 1: v -> g_vt transpose/convert, + z_pb ----------------
__global__ __launch_bounds__(256) void prep_kernel(const float* __restrict__ v,
                                                   const float* __restrict__ w,
                                                   float* __restrict__ out) {
  __shared__ float zls[4096];   // zpb: wv[2048] + pfx[2048]
  __shared__ float wsum[4];

  const int bx  = blockIdx.x;
  const int tid = threadIdx.x;

  if (bx >= 384) {   // ---- zpb: z[i+1] = P[i] + P[2045-i] - w[h,0] ----
    const int h = bx - 384;
    float* wvv = zls;          // [2048]
    float* pfx = zls + 2048;   // [2048]
    const float* wh = w + (size_t)h * 2048;
    float* zout = out + 6291456;
    for (int i = tid; i < 2048; i += 256) wvv[i] = (i < 2046) ? wh[i] : 0.f;
    __syncthreads();
    const int base = tid * 8;
    float run0 = 0.f;
    #pragma unroll
    for (int k = 0; k < 8; ++k) run0 += wvv[base + k];
    float x = run0;
    #pragma unroll
    for (int dd = 1; dd < 64; dd <<= 1) {
      float y = __shfl_up(x, dd);
      if ((tid & 63) >= dd) x += y;
    }
    if ((tid & 63) == 63) wsum[tid >> 6] = x;
    __syncthreads();
    const int wid4 = tid >> 6;
    float woff = 0.f;
    #pragma unroll
    for (int u = 0; u < 3; ++u) { float t = wsum[u]; if (u < wid4) woff += t; }
    float pr = x + woff - run0;
    #pragma unroll
    for (int k = 0; k < 8; ++k) { pr += wvv[base + k]; pfx[base + k] = pr; }
    __syncthreads();
    for (int i = tid; i < 2046; i += 256) {
      float z = pfx[i] + pfx[2045 - i] - wvv[0];
      zout[(size_t)(i + 1) * 12 + h] = z;
    }
    if (tid == 0) { zout[h] = 0.f; zout[(size_t)2047 * 12 + h] = 0.f; }
    return;
  }

  // ---- transpose/convert: block = (n, h, 256-l chunk); wave = 64-l sub-chunk ----
  const int chunk = bx & 7;
  const int slice = bx >> 3;            // 0..47
  const int n = slice / 12, h = slice - n * 12;
  const int lane = tid & 63;            // d
  const int wv   = tid >> 6;            // 0..3
  const int l0 = chunk * 256 + wv * 64;

  // reads: lanes 0..63 cover d=0..63 at fixed l -> 256 B fully-coalesced per instr
  const float* src = v + (((size_t)n * 2048 + l0) * 12 + h) * 64 + lane;
  short* dst = g_vt + (((size_t)n * 12 + h) * 64 + lane) * 2048 + l0;

  #pragma unroll
  for (int k = 0; k < 8; ++k) {
    float f[8];
    #pragma unroll
    for (int i = 0; i < 8; ++i) f[i] = src[(size_t)(k * 8 + i) * 768];
    short8 b;
    #pragma unroll
    for (int i = 0; i < 8; ++i) {
      int l = l0 + k * 8 + i;
      b[i] = (l == 0 || l == 2047) ? (short)0 : (short)f2bf(f[i]);
    }
    *(short8*)&dst[k * 8] = b;  // 16 B aligned store (l0, k*8 multiples of 8 shorts)
  }
}

// ---------------- dispatch 2: Toeplitz GEMM, 128j x 64nd per block ----------------
__global__ __launch_bounds__(256, 3) void gemm_kernel(const float* __restrict__ w,
                                                      float* __restrict__ out) {
  __shared__ __attribute__((aligned(16))) short Tls[8 * TL];  // 36.5 KB

  const int bx  = blockIdx.x;
  const int tid = threadIdx.x;

  // Same-slice blocks are 48 apart in linear id (48%8==0) -> same XCD -> vt-slice L2-resident.
  const int slice = bx % 48;          // (h, ndt)
  const int jt    = bx / 48;          // 16 j-tiles
  const int ndt = slice & 3;          // batch n for the whole block
  const int h   = slice >> 2;
  const int lane = tid & 63, wid = tid >> 6;
  const int lm = lane & 15, quad = lane >> 4;
  const int jb = jt * 128;
  const int d  = wid * 16 + lm;       // lane's head-dim index (wave owns a 16-d strip)

  // B source: bf16 v^T row at (ndt,h,d); per instr: 4 quads x 8 l x 16 d = 16 fully-used
  // 64B lines. One dwordx4 per lane IS the MFMA B-fragment (borders pre-zeroed in prep).
  const short* vtb = g_vt + (((size_t)ndt * 12 + h) * 64 + d) * 2048;

  // issue t=0 B-frags before the table build (latency hidden under build VALU)
  short8 bc0 = *(const short8*)&vtb[quad * 8];
  short8 bc1 = *(const short8*)&vtb[32 + quad * 8];

  // build reversed, 8x-shifted Toeplitz table: T_c[p] = w_ext[127 + jb - p - c]
  const float* wh = w + (size_t)h * 2048;
  for (int g = tid; g < 8 * (TL / 8); g += 256) {
    int c  = g / (TL / 8);
    int p8 = (g - c * (TL / 8)) * 8;
    unsigned short buf[8] __attribute__((aligned(16)));
    #pragma unroll
    for (int i = 0; i < 8; ++i) {
      int t = 127 + jb - (p8 + i) - c;
      int a = t < 0 ? -t : t;
      buf[i] = (a <= 2045) ? f2bf(wh[a]) : (unsigned short)0;
    }
    *(short8*)&Tls[c * TL + p8] = *(const short8*)buf;
  }
  __syncthreads();   // the only block-wide sync

  // A-frag: value[i] = w_ext[j - k], j = jb + ma*16 + lm, k = l0 + kc*32 + quad*8 + i
  // p0 = l0 + 16*g + pbase, g = 2*kc - ma in [-7,2]; aligned b128 from copy (p0 & 7).
  const int pbase = 127 + quad * 8 - lm;
  auto load_af = [&](int p0) -> short8 {
    int c = p0 & 7;
    return *(const short8*)&Tls[c * TL + (p0 - c)];
  };

  short8 afr[10];                      // afr[i] = diagonal g = i-7 relative to current l0
  #pragma unroll
  for (int i = 0; i < 10; ++i) afr[i] = load_af((i - 7) * 16 + pbase);

  floatx4 acc[8];
  #pragma unroll
  for (int ma = 0; ma < 8; ++ma) acc[ma] = (floatx4){0.f, 0.f, 0.f, 0.f};

  #pragma unroll 4
  for (int t = 0; t < 32; ++t) {
    const int l0 = t * 64;
    // B prefetch distance 1 (tail clamp re-reads t=31: harmless)
    const int lb = ((t < 31) ? (t + 1) : 31) * 64 + quad * 8;
    short8 bn0 = *(const short8*)&vtb[lb];
    short8 bn1 = *(const short8*)&vtb[lb + 32];
    // A prefetch distance 1: next iter's fresh diagonals g = -1,0,1,2
    const int l0n = (t < 31) ? l0 + 64 : l0;
    short8 na0 = load_af(l0n - 16 + pbase);
    short8 na1 = load_af(l0n      + pbase);
    short8 na2 = load_af(l0n + 16 + pbase);
    short8 na3 = load_af(l0n + 32 + pbase);

    #pragma unroll
    for (int ma = 0; ma < 8; ++ma)   // kc=0: g = -ma  -> idx 7-ma
      acc[ma] = __builtin_amdgcn_mfma_f32_16x16x32_bf16(afr[7 - ma], bc0, acc[ma], 0, 0, 0);
    #pragma unroll
    for (int ma = 0; ma < 8; ++ma)   // kc=1: g = 2-ma -> idx 9-ma
      acc[ma] = __builtin_amdgcn_mfma_f32_16x16x32_bf16(afr[9 - ma], bc1, acc[ma], 0, 0, 0);

    // rotate pipelines
    bc0 = bn0; bc1 = bn1;
    #pragma unroll
    for (int i = 0; i < 6; ++i) afr[i] = afr[i + 4];
    afr[6] = na0; afr[7] = na1; afr[8] = na2; afr[9] = na3;
  }

  // epilogue: D row = quad*4 + r (j), col = lm (d); zero rows j=0 and j=2047
  float* obase = out + (size_t)ndt * 1572864 + (size_t)h * 64 + d;
  #pragma unroll
  for (int ma = 0; ma < 8; ++ma) {
    floatx4 cc = acc[ma];
    #pragma unroll
    for (int r = 0; r < 4; ++r) {
      int j = jb + ma * 16 + quad * 4 + r;
      float val = (j == 0 || j == 2047) ? 0.f : cc[r];
      obase[(size_t)j * 768] = val;
    }
  }
}

extern "C" void kernel_launch(void* const* d_in, const int* in_sizes, int n_in,
                              void* d_out, int out_size, void* d_ws, size_t ws_size,
                              hipStream_t stream) {
  const float* v = (const float*)d_in[0];   // (4,2048,12,64) fp32
  const float* w = (const float*)d_in[1];   // (12,2048) fp32
  float* out = (float*)d_out;               // pbv (6291456) + z_pb (24576) fp32
  prep_kernel<<<dim3(396), 256, 0, stream>>>(v, w, out);
  gemm_kernel<<<dim3(768), 256, 0, stream>>>(w, out);
}

// Round 2
// 128.421 us; speedup vs baseline: 1.0103x; 1.0103x over previous
//
#include <hip/hip_runtime.h>
#include <hip/hip_bf16.h>

// PositionalBias: pbv[n,j,h,d] = sum_{l=1..2046} w[h,|j-l|] * v[n,l,h,d]  (j in 1..2046, else 0)
//                 z_pb[l,h]    = sum_{j=1..2046} w[h,|l-j|]               (l in 1..2046, else 0)
// B=4, S=2048, H=12, D=64. Outputs fp32: pbv (6291456) then z_pb (24576).
//
// TWO dispatches:
//  1) prep_kernel (408 blocks):
//     0..383  : transpose+convert v -> g_vt[n][h][d][l] bf16, borders l=0/2047 zeroed
//     384..395: z_pb
//     396..407: A fragment table g_wt: F[h][8q+i] = bf16(w_ext[2174 - q - i]).
//               Every 16B slot q IS a ready MFMA A-fragment (pre-expanded 8-shifted copies;
//               interleaved layout [q/8][shift][i] collapses to 8q+i).
//  2) gemm_kernel (768 blocks, NO LDS, NO barriers): pure register pipeline.
//     Per iter per wave: 4 A dwordx4 (L1-hot, distance 1) + 2 B dwordx4 (L2, distance 2)
//     + 16 MFMA under setprio. Full unroll -> static rotation, single vmcnt wait domain.

typedef short short8 __attribute__((ext_vector_type(8)));   // 8 x bf16 bits (4 VGPRs)
typedef float floatx4 __attribute__((ext_vector_type(4)));  // MFMA accumulator

#define QN 4288   // A-table fragment slots per h (q in [0,4288), need max 4214)

__device__ __attribute__((aligned(16))) short g_vt[4 * 12 * 64 * 2048];  // 12.6 MB
__device__ __attribute__((aligned(16))) short g_wt[12 * QN * 8];         // 823 KB

__device__ __forceinline__ unsigned short f2bf(float f) {
  union { __hip_bfloat16 b; unsigned short u; } cv;
  cv.b = __float2bfloat16(f);  // RNE
  return cv.u;
}

// ---------------- dispatch 1: v -> g_vt, z_pb, w -> g_wt ----------------
__global__ __launch_bounds__(256) void prep_kernel(const float* __restrict__ v,
                                                   const float* __restrict__ w,
                                                   float* __restrict__ out) {
  __shared__ float zls[4096];
  __shared__ float wsum[4];

  const int bx  = blockIdx.x;
  const int tid = threadIdx.x;

  if (bx >= 396) {   // ---- A fragment table for h = bx-396 ----
    const int h = bx - 396;
    const float* wh = w + (size_t)h * 2048;
    short* F = g_wt + (size_t)h * QN * 8;
    for (int q = tid; q < QN; q += 256) {
      unsigned short buf[8] __attribute__((aligned(16)));
      #pragma unroll
      for (int i = 0; i < 8; ++i) {
        int t = 2174 - q - i;
        int a = t < 0 ? -t : t;
        buf[i] = (a <= 2045) ? f2bf(wh[a]) : (unsigned short)0;
      }
      *(short8*)&F[(size_t)q * 8] = *(const short8*)buf;
    }
    return;
  }

  if (bx >= 384) {   // ---- zpb: z[i+1] = P[i] + P[2045-i] - w[h,0] ----
    const int h = bx - 384;
    float* wvv = zls;          // [2048]
    float* pfx = zls + 2048;   // [2048]
    const float* wh = w + (size_t)h * 2048;
    float* zout = out + 6291456;
    for (int i = tid; i < 2048; i += 256) wvv[i] = (i < 2046) ? wh[i] : 0.f;
    __syncthreads();
    const int base = tid * 8;
    float run0 = 0.f;
    #pragma unroll
    for (int k = 0; k < 8; ++k) run0 += wvv[base + k];
    float x = run0;
    #pragma unroll
    for (int dd = 1; dd < 64; dd <<= 1) {
      float y = __shfl_up(x, dd);
      if ((tid & 63) >= dd) x += y;
    }
    if ((tid & 63) == 63) wsum[tid >> 6] = x;
    __syncthreads();
    const int wid4 = tid >> 6;
    float woff = 0.f;
    #pragma unroll
    for (int u = 0; u < 3; ++u) { float t = wsum[u]; if (u < wid4) woff += t; }
    float pr = x + woff - run0;
    #pragma unroll
    for (int k = 0; k < 8; ++k) { pr += wvv[base + k]; pfx[base + k] = pr; }
    __syncthreads();
    for (int i = tid; i < 2046; i += 256) {
      float z = pfx[i] + pfx[2045 - i] - wvv[0];
      zout[(size_t)(i + 1) * 12 + h] = z;
    }
    if (tid == 0) { zout[h] = 0.f; zout[(size_t)2047 * 12 + h] = 0.f; }
    return;
  }

  // ---- transpose/convert: block = (n, h, 256-l chunk); wave = 64-l sub-chunk ----
  const int chunk = bx & 7;
  const int slice = bx >> 3;            // 0..47
  const int n = slice / 12, h = slice - n * 12;
  const int lane = tid & 63;            // d
  const int wv   = tid >> 6;            // 0..3
  const int l0 = chunk * 256 + wv * 64;

  const float* src = v + (((size_t)n * 2048 + l0) * 12 + h) * 64 + lane;
  short* dst = g_vt + (((size_t)n * 12 + h) * 64 + lane) * 2048 + l0;

  #pragma unroll
  for (int k = 0; k < 8; ++k) {
    float f[8];
    #pragma unroll
    for (int i = 0; i < 8; ++i) f[i] = src[(size_t)(k * 8 + i) * 768];
    short8 b;
    #pragma unroll
    for (int i = 0; i < 8; ++i) {
      int l = l0 + k * 8 + i;
      b[i] = (l == 0 || l == 2047) ? (short)0 : (short)f2bf(f[i]);
    }
    *(short8*)&dst[k * 8] = b;
  }
}

// ---------------- dispatch 2: Toeplitz GEMM, 128j x 64nd per block, no LDS ----------------
__global__ __launch_bounds__(256, 3) void gemm_kernel(float* __restrict__ out) {
  const int bx  = blockIdx.x;
  const int tid = threadIdx.x;

  // Same-slice blocks are 48 apart (48%8==0) -> same XCD -> vt-slice + A-table L2-resident.
  const int slice = bx % 48;          // (h, ndt)
  const int jt    = bx / 48;          // 16 j-tiles
  const int ndt = slice & 3;
  const int h   = slice >> 2;
  const int lane = tid & 63;
  const int wid  = tid >> 6;
  const int lm = lane & 15, quad = lane >> 4;
  const int jb = jt * 128;
  const int d  = wid * 16 + lm;       // wave owns a 16-d strip

  // B: bf16 v^T row (borders pre-zeroed). One dwordx4 IS the B-fragment.
  const short* vtb = g_vt + (((size_t)ndt * 12 + h) * 64 + d) * 2048;
  // A: fragment value_i = w_ext[127 + jb - p0 - i]; with q = p0 + (2047-jb):
  //    F[h][8q+i] = w_ext[2174-q-i]. q = l0 + 16*g + lane_base. Identical for all 4 waves.
  const short* wtb = g_wt + (size_t)h * QN * 8;
  const int lane_base = 127 + quad * 8 - lm + 2047 - jb;

  auto load_af = [&](int q) -> short8 {
    return *(const short8*)&wtb[(size_t)q << 3];   // byte offset q*16, aligned
  };
  auto load_bf = [&](int lb) -> short8 {
    return *(const short8*)&vtb[lb];
  };

  // prologue: A window (diagonals g=-7..2 rel. l0=0) + B for t=0,1
  short8 afr[10];
  #pragma unroll
  for (int i = 0; i < 10; ++i) afr[i] = load_af((i - 7) * 16 + lane_base);
  short8 bc0 = load_bf(quad * 8);
  short8 bc1 = load_bf(32 + quad * 8);
  short8 bn0 = load_bf(64 + quad * 8);
  short8 bn1 = load_bf(96 + quad * 8);

  floatx4 acc[8];
  #pragma unroll
  for (int ma = 0; ma < 8; ++ma) acc[ma] = (floatx4){0.f, 0.f, 0.f, 0.f};

  #pragma unroll
  for (int t = 0; t < 32; ++t) {       // full unroll: all indices static, rotation = renaming
    // B prefetch distance 2
    short8 bm0, bm1;
    if (t < 30) {
      const int lb = (t + 2) * 64 + quad * 8;
      bm0 = load_bf(lb);
      bm1 = load_bf(lb + 32);
    }
    // A prefetch distance 1: next iter's fresh diagonals g' = -1,0,1,2
    short8 na0, na1, na2, na3;
    if (t < 31) {
      const int l0n = t * 64 + 64;
      na0 = load_af(l0n - 16 + lane_base);
      na1 = load_af(l0n      + lane_base);
      na2 = load_af(l0n + 16 + lane_base);
      na3 = load_af(l0n + 32 + lane_base);
    }

    __builtin_amdgcn_s_setprio(1);
    #pragma unroll
    for (int ma = 0; ma < 8; ++ma)   // kc=0: g = -ma  -> idx 7-ma
      acc[ma] = __builtin_amdgcn_mfma_f32_16x16x32_bf16(afr[7 - ma], bc0, acc[ma], 0, 0, 0);
    #pragma unroll
    for (int ma = 0; ma < 8; ++ma)   // kc=1: g = 2-ma -> idx 9-ma
      acc[ma] = __builtin_amdgcn_mfma_f32_16x16x32_bf16(afr[9 - ma], bc1, acc[ma], 0, 0, 0);
    __builtin_amdgcn_s_setprio(0);

    if (t < 31) {
      #pragma unroll
      for (int i = 0; i < 6; ++i) afr[i] = afr[i + 4];
      afr[6] = na0; afr[7] = na1; afr[8] = na2; afr[9] = na3;
      bc0 = bn0; bc1 = bn1;
      if (t < 30) { bn0 = bm0; bn1 = bm1; }
    }
  }

  // epilogue: D row = quad*4 + r (j), col = lm (d); zero rows j=0 and j=2047
  float* obase = out + (size_t)ndt * 1572864 + (size_t)h * 64 + d;
  #pragma unroll
  for (int ma = 0; ma < 8; ++ma) {
    floatx4 cc = acc[ma];
    #pragma unroll
    for (int r = 0; r < 4; ++r) {
      int j = jb + ma * 16 + quad * 4 + r;
      float val = (j == 0 || j == 2047) ? 0.f : cc[r];
      obase[(size_t)j * 768] = val;
    }
  }
}

extern "C" void kernel_launch(void* const* d_in, const int* in_sizes, int n_in,
                              void* d_out, int out_size, void* d_ws, size_t ws_size,
                              hipStream_t stream) {
  const float* v = (const float*)d_in[0];   // (4,2048,12,64) fp32
  const float* w = (const float*)d_in[1];   // (12,2048) fp32
  float* out = (float*)d_out;               // pbv (6291456) + z_pb (24576) fp32
  prep_kernel<<<dim3(408), 256, 0, stream>>>(v, w, out);
  gemm_kernel<<<dim3(768), 256, 0, stream>>>(out);
}

// Round 3
// 122.083 us; speedup vs baseline: 1.0628x; 1.0519x over previous
//
#include <hip/hip_runtime.h>
#include <hip/hip_bf16.h>

// PositionalBias: pbv[n,j,h,d] = sum_{l=1..2046} w[h,|j-l|] * v[n,l,h,d]  (j in 1..2046, else 0)
//                 z_pb[l,h]    = sum_{j=1..2046} w[h,|l-j|]               (l in 1..2046, else 0)
// B=4, S=2048, H=12, D=64. Outputs fp32: pbv (6291456) then z_pb (24576).
//
// TWO dispatches:
//  1) prep_kernel (1560 blocks):
//     0..1535   : transpose+convert v -> g_vt[n][h][d][l] bf16 (64-l chunks for TLP),
//                 borders l=0/2047 zeroed
//     1536..1547: z_pb
//     1548..1559: A fragment table g_wt: F[h][8q+i] = bf16(w_ext[2174 - q - i]).
//                 Every 16B slot q IS a ready MFMA A-fragment.
//  2) gemm_kernel (768 blocks): per block, copy its 2304-slot A-window from g_wt into LDS
//     (pure coalesced copy, no VALU expansion), then per iter per wave:
//     4 ds_read_b128 (A, 2-way bank alias = free) + 2 global dwordx4 (B, distance-2)
//     + 16 MFMA under setprio. Split wait domains (A=lgkm, B=vm) pipeline well in hipcc.

typedef short short8 __attribute__((ext_vector_type(8)));   // 8 x bf16 bits (4 VGPRs)
typedef float floatx4 __attribute__((ext_vector_type(4)));  // MFMA accumulator

#define QN 4352   // A-table fragment slots per h; max read = qbase(jb=0)+2303 = 4350

__device__ __attribute__((aligned(16))) short g_vt[4 * 12 * 64 * 2048];  // 12.6 MB
__device__ __attribute__((aligned(16))) short g_wt[12 * QN * 8];         // 835 KB

__device__ __forceinline__ unsigned short f2bf(float f) {
  union { __hip_bfloat16 b; unsigned short u; } cv;
  cv.b = __float2bfloat16(f);  // RNE
  return cv.u;
}

// ---------------- dispatch 1: v -> g_vt, z_pb, w -> g_wt ----------------
__global__ __launch_bounds__(256) void prep_kernel(const float* __restrict__ v,
                                                   const float* __restrict__ w,
                                                   float* __restrict__ out) {
  __shared__ float zls[4096];
  __shared__ float wsum[4];

  const int bx  = blockIdx.x;
  const int tid = threadIdx.x;

  if (bx >= 1548) {   // ---- A fragment table for h = bx-1548 ----
    const int h = bx - 1548;
    const float* wh = w + (size_t)h * 2048;
    short* F = g_wt + (size_t)h * QN * 8;
    for (int q = tid; q < QN; q += 256) {
      unsigned short buf[8] __attribute__((aligned(16)));
      #pragma unroll
      for (int i = 0; i < 8; ++i) {
        int t = 2174 - q - i;
        int a = t < 0 ? -t : t;
        buf[i] = (a <= 2045) ? f2bf(wh[a]) : (unsigned short)0;
      }
      *(short8*)&F[(size_t)q * 8] = *(const short8*)buf;
    }
    return;
  }

  if (bx >= 1536) {   // ---- zpb: z[i+1] = P[i] + P[2045-i] - w[h,0] ----
    const int h = bx - 1536;
    float* wvv = zls;          // [2048]
    float* pfx = zls + 2048;   // [2048]
    const float* wh = w + (size_t)h * 2048;
    float* zout = out + 6291456;
    for (int i = tid; i < 2048; i += 256) wvv[i] = (i < 2046) ? wh[i] : 0.f;
    __syncthreads();
    const int base = tid * 8;
    float run0 = 0.f;
    #pragma unroll
    for (int k = 0; k < 8; ++k) run0 += wvv[base + k];
    float x = run0;
    #pragma unroll
    for (int dd = 1; dd < 64; dd <<= 1) {
      float y = __shfl_up(x, dd);
      if ((tid & 63) >= dd) x += y;
    }
    if ((tid & 63) == 63) wsum[tid >> 6] = x;
    __syncthreads();
    const int wid4 = tid >> 6;
    float woff = 0.f;
    #pragma unroll
    for (int u = 0; u < 3; ++u) { float t = wsum[u]; if (u < wid4) woff += t; }
    float pr = x + woff - run0;
    #pragma unroll
    for (int k = 0; k < 8; ++k) { pr += wvv[base + k]; pfx[base + k] = pr; }
    __syncthreads();
    for (int i = tid; i < 2046; i += 256) {
      float z = pfx[i] + pfx[2045 - i] - wvv[0];
      zout[(size_t)(i + 1) * 12 + h] = z;
    }
    if (tid == 0) { zout[h] = 0.f; zout[(size_t)2047 * 12 + h] = 0.f; }
    return;
  }

  // ---- transpose/convert: block = (n, h, 64-l chunk); thread = (d=lane, 16-l sub) ----
  const int chunk = bx & 31;            // 32 chunks of 64 l
  const int slice = bx >> 5;            // 0..47
  const int n = slice / 12, h = slice - n * 12;
  const int lane = tid & 63;            // d
  const int wv   = tid >> 6;            // 0..3
  const int l0 = chunk * 64 + wv * 16;

  const float* src = v + (((size_t)n * 2048 + l0) * 12 + h) * 64 + lane;
  short* dst = g_vt + (((size_t)n * 12 + h) * 64 + lane) * 2048 + l0;

  float f[16];
  #pragma unroll
  for (int k = 0; k < 16; ++k) f[k] = src[(size_t)k * 768];
  #pragma unroll
  for (int g = 0; g < 2; ++g) {
    short8 b;
    #pragma unroll
    for (int i = 0; i < 8; ++i) {
      int l = l0 + g * 8 + i;
      b[i] = (l == 0 || l == 2047) ? (short)0 : (short)f2bf(f[g * 8 + i]);
    }
    *(short8*)&dst[g * 8] = b;
  }
}

// ---------------- dispatch 2: Toeplitz GEMM, 128j x 64nd per block ----------------
__global__ __launch_bounds__(256, 3) void gemm_kernel(float* __restrict__ out) {
  __shared__ __attribute__((aligned(16))) short Als[2304 * 8];  // 36,864 B

  const int bx  = blockIdx.x;
  const int tid = threadIdx.x;

  // Same-slice blocks are 48 apart (48%8==0) -> same XCD -> vt-slice + A-window L2-resident.
  const int slice = bx % 48;          // (h, ndt)
  const int jt    = bx / 48;          // 16 j-tiles
  const int ndt = slice & 3;
  const int h   = slice >> 2;
  const int lane = tid & 63;
  const int wid  = tid >> 6;
  const int lm = lane & 15, quad = lane >> 4;
  const int jb = jt * 128;
  const int d  = wid * 16 + lm;       // wave owns a 16-d strip

  // B: bf16 v^T row (borders pre-zeroed). One dwordx4 IS the B-fragment.
  const short* vtb = g_vt + (((size_t)ndt * 12 + h) * 64 + d) * 2048;
  auto load_bf = [&](int lb) -> short8 {
    return *(const short8*)&vtb[lb];
  };

  // issue t=0,1 B-frags first: latency hides under the A-window copy
  short8 bc0 = load_bf(quad * 8);
  short8 bc1 = load_bf(32 + quad * 8);
  short8 bn0 = load_bf(64 + quad * 8);
  short8 bn1 = load_bf(96 + quad * 8);

  // copy this block's A-window g_wt[h][qbase .. qbase+2303] -> LDS (coalesced, no VALU)
  const short* wsrc = g_wt + (size_t)h * QN * 8 + (size_t)(2047 - jb) * 8;
  #pragma unroll
  for (int k = 0; k < 9; ++k) {
    *(short8*)&Als[(size_t)(k * 256 + tid) * 8] =
        *(const short8*)&wsrc[(size_t)(k * 256 + tid) * 8];
  }
  __syncthreads();   // the only block-wide sync

  // A-frag at slot p+abase (16B each): value_i = w_ext[j - k] for this lane's (quad,lm).
  // p = l0 + 16*g, abase = 127 + quad*8 - lm; lanes lm/lm+8 alias banks -> 2-way (free).
  const int abase = 127 + quad * 8 - lm;
  auto load_af = [&](int p) -> short8 {
    return *(const short8*)&Als[(size_t)(p + abase) * 8];
  };

  short8 afr[10];                      // afr[i] = diagonal g = i-7 relative to current l0
  #pragma unroll
  for (int i = 0; i < 10; ++i) afr[i] = load_af((i - 7) * 16);

  floatx4 acc[8];
  #pragma unroll
  for (int ma = 0; ma < 8; ++ma) acc[ma] = (floatx4){0.f, 0.f, 0.f, 0.f};

  #pragma unroll 4
  for (int t = 0; t < 32; ++t) {
    const int l0 = t * 64;
    // B prefetch distance 2 (branchless clamp; tail re-reads t=31: harmless)
    int t2 = t + 2; if (t2 > 31) t2 = 31;
    const int lb = t2 * 64 + quad * 8;
    short8 bm0 = load_bf(lb);
    short8 bm1 = load_bf(lb + 32);
    // A prefetch distance 1: next iter's fresh diagonals g = -1,0,1,2
    const int l0n = (t < 31) ? l0 + 64 : l0;
    short8 na0 = load_af(l0n - 16);
    short8 na1 = load_af(l0n);
    short8 na2 = load_af(l0n + 16);
    short8 na3 = load_af(l0n + 32);

    __builtin_amdgcn_s_setprio(1);
    #pragma unroll
    for (int ma = 0; ma < 8; ++ma)   // kc=0: g = -ma  -> idx 7-ma
      acc[ma] = __builtin_amdgcn_mfma_f32_16x16x32_bf16(afr[7 - ma], bc0, acc[ma], 0, 0, 0);
    #pragma unroll
    for (int ma = 0; ma < 8; ++ma)   // kc=1: g = 2-ma -> idx 9-ma
      acc[ma] = __builtin_amdgcn_mfma_f32_16x16x32_bf16(afr[9 - ma], bc1, acc[ma], 0, 0, 0);
    __builtin_amdgcn_s_setprio(0);

    // rotate pipelines
    #pragma unroll
    for (int i = 0; i < 6; ++i) afr[i] = afr[i + 4];
    afr[6] = na0; afr[7] = na1; afr[8] = na2; afr[9] = na3;
    bc0 = bn0; bc1 = bn1;
    bn0 = bm0; bn1 = bm1;
  }

  // epilogue: D row = quad*4 + r (j), col = lm (d); zero rows j=0 and j=2047
  float* obase = out + (size_t)ndt * 1572864 + (size_t)h * 64 + d;
  #pragma unroll
  for (int ma = 0; ma < 8; ++ma) {
    floatx4 cc = acc[ma];
    #pragma unroll
    for (int r = 0; r < 4; ++r) {
      int j = jb + ma * 16 + quad * 4 + r;
      float val = (j == 0 || j == 2047) ? 0.f : cc[r];
      obase[(size_t)j * 768] = val;
    }
  }
}

extern "C" void kernel_launch(void* const* d_in, const int* in_sizes, int n_in,
                              void* d_out, int out_size, void* d_ws, size_t ws_size,
                              hipStream_t stream) {
  const float* v = (const float*)d_in[0];   // (4,2048,12,64) fp32
  const float* w = (const float*)d_in[1];   // (12,2048) fp32
  float* out = (float*)d_out;               // pbv (6291456) + z_pb (24576) fp32
  prep_kernel<<<dim3(1560), 256, 0, stream>>>(v, w, out);
  gemm_kernel<<<dim3(768), 256, 0, stream>>>(out);
}